// Round 5
// baseline (3338.261 us; speedup 1.0000x reference)
//
#include <hip/hip_runtime.h>
#include <cmath>

#define TT 256
#define BB 512
#define DD 128
#define HH 128
#define NCOL 528   // 4*H + 16 quantum-angle cols
#define KK 256
#define NCPAD 576  // 9 * 64

// ---------------- weight pack ----------------
// Wxp[528][128]            : x-half, row-major (for xgemm LDS staging)
// Whr[j][kh][col] float4   : h-half main cols, k-outer so rec's per-lane loads coalesce
// Whqr[j][kh][qc] float4   : h-half quantum-angle cols
// bcat[576]
__global__ __launch_bounds__(256) void pack_weights(
    const float* __restrict__ Wf, const float* __restrict__ bf,
    const float* __restrict__ Wfq, const float* __restrict__ bfq,
    const float* __restrict__ Wi, const float* __restrict__ bi,
    const float* __restrict__ Wiq, const float* __restrict__ biq,
    const float* __restrict__ Wg, const float* __restrict__ bg,
    const float* __restrict__ Wgq, const float* __restrict__ bgq,
    const float* __restrict__ Wo, const float* __restrict__ bo,
    const float* __restrict__ Woq, const float* __restrict__ boq,
    float* __restrict__ Wxp, float* __restrict__ Whr,
    float* __restrict__ Whqr, float* __restrict__ bcat)
{
    int idx = blockIdx.x * blockDim.x + threadIdx.x;
    if (idx < NCOL * KK) {
        int c = idx >> 8, k = idx & 255;
        const float* srcW; int cl;
        if (c < 512) { int g = c >> 7; cl = c & 127;
            srcW = (g == 0) ? Wf : (g == 1) ? Wi : (g == 2) ? Wg : Wo; }
        else { int g = (c - 512) >> 2; cl = (c - 512) & 3;
            srcW = (g == 0) ? Wfq : (g == 1) ? Wiq : (g == 2) ? Wgq : Woq; }
        float v = srcW[(size_t)cl * KK + k];
        if (k < 128) Wxp[(size_t)c * 128 + k] = v;
        else {
            int kk = k - 128;
            int khalf = kk >> 6;          // 0/1
            int jj = (kk & 63) >> 2;      // 0..15 float4 index within half
            int e  = kk & 3;
            if (c < 512) Whr [((size_t)(jj * 2 + khalf) * 512 + c)        * 4 + e] = v;
            else         Whqr[((size_t)(jj * 2 + khalf) * 16  + (c - 512)) * 4 + e] = v;
        }
    }
    if (idx < NCPAD) {
        float b = 0.f;
        int c = idx;
        if (c < 512) { int g = c >> 7; int cl = c & 127;
            b = (g == 0) ? bf[cl] : (g == 1) ? bi[cl] : (g == 2) ? bg[cl] : bo[cl]; }
        else if (c < NCOL) { int g = (c - 512) >> 2; int cl = (c - 512) & 3;
            b = (g == 0) ? bfq[cl] : (g == 1) ? biq[cl] : (g == 2) ? bgq[cl] : boq[cl]; }
        bcat[c] = b;
    }
}

// ---------------- phase 1: Zx = X @ Wx^T + bcat  (M x 528, K=128) ----------------
#define P1_BM 128
#define P1_BN 64
#define ATP 132   // padded leading dims: cut staging-write bank conflicts 16->8-way
#define BTP 68
__global__ __launch_bounds__(256, 3) void xgemm(
    const float* __restrict__ X, const float* __restrict__ Wxp,
    const float* __restrict__ bcat, float* __restrict__ Zx)
{
    __shared__ float At[64][ATP];
    __shared__ float Bt[64][BTP];
    const int tid = threadIdx.x;
    const int m0 = blockIdx.x * P1_BM;
    const int c0 = blockIdx.y * P1_BN;
    const int tm = tid >> 3;   // 0..31 -> rows tm*4 (lanes hit distinct bank-groups)
    const int tn = tid & 7;    // 0..7  -> cols tn*8 (2-way, free)
    float acc[4][8] = {};

    for (int khf = 0; khf < 2; ++khf) {
        #pragma unroll
        for (int j = 0; j < 8; ++j) {
            int fidx = tid + 256 * j;            // 0..2047
            int m = fidx >> 4, k4 = (fidx & 15) * 4;
            float4 v = *(const float4*)(X + (size_t)(m0 + m) * 128 + khf * 64 + k4);
            At[k4 + 0][m] = v.x; At[k4 + 1][m] = v.y; At[k4 + 2][m] = v.z; At[k4 + 3][m] = v.w;
        }
        #pragma unroll
        for (int j = 0; j < 4; ++j) {
            int fidx = tid + 256 * j;            // 0..1023
            int c = fidx >> 4, k4 = (fidx & 15) * 4;
            int cg = c0 + c;
            float4 v = make_float4(0.f, 0.f, 0.f, 0.f);
            if (cg < NCOL) v = *(const float4*)(Wxp + (size_t)cg * 128 + khf * 64 + k4);
            Bt[k4 + 0][c] = v.x; Bt[k4 + 1][c] = v.y; Bt[k4 + 2][c] = v.z; Bt[k4 + 3][c] = v.w;
        }
        __syncthreads();
        #pragma unroll 4
        for (int k = 0; k < 64; ++k) {
            float4 a  = *(const float4*)&At[k][tm * 4];
            float4 b0 = *(const float4*)&Bt[k][tn * 8];
            float4 b1 = *(const float4*)&Bt[k][tn * 8 + 4];
            float av[4] = {a.x, a.y, a.z, a.w};
            float bv[8] = {b0.x, b0.y, b0.z, b0.w, b1.x, b1.y, b1.z, b1.w};
            #pragma unroll
            for (int i = 0; i < 4; ++i)
                #pragma unroll
                for (int j = 0; j < 8; ++j)
                    acc[i][j] = fmaf(av[i], bv[j], acc[i][j]);
        }
        __syncthreads();
    }
    int c = c0 + tn * 8;
    if (c < NCOL) {
        float4 ba = *(const float4*)(bcat + c);
        float4 bb = *(const float4*)(bcat + c + 4);
        #pragma unroll
        for (int i = 0; i < 4; ++i) {
            int m = m0 + tm * 4 + i;
            float4 o0, o1;
            o0.x = acc[i][0] + ba.x; o0.y = acc[i][1] + ba.y;
            o0.z = acc[i][2] + ba.z; o0.w = acc[i][3] + ba.w;
            o1.x = acc[i][4] + bb.x; o1.y = acc[i][5] + bb.y;
            o1.z = acc[i][6] + bb.z; o1.w = acc[i][7] + bb.w;
            *(float4*)(Zx + (size_t)m * NCOL + c)     = o0;
            *(float4*)(Zx + (size_t)m * NCOL + c + 4) = o1;
        }
    }
}

// ---------------- phase 2: recurrence ----------------
__device__ __forceinline__ float sigm(float x) { return 1.0f / (1.0f + __expf(-x)); }
__device__ __forceinline__ float tanh_f(float x) {
    float e = __expf(2.f * x);
    return 1.f - 2.f / (e + 1.f);
}

// NOTE: macro params must NOT be named x/y/z/w.
#define FMA4(acc, Wv, Xv) acc = fmaf((Wv).x, (Xv).x, fmaf((Wv).y, (Xv).y, fmaf((Wv).z, (Xv).z, fmaf((Wv).w, (Xv).w, (acc)))))
#define PIN4(Wv) asm volatile("" : "+v"((Wv).x), "+v"((Wv).y), "+v"((Wv).z), "+v"((Wv).w))

__global__ __launch_bounds__(1024)
__attribute__((amdgpu_waves_per_eu(4, 4)))   // 512-VGPR budget: keep weights resident, no spill
void qlstm_rec(
    const float* __restrict__ Zx,      // [TC][512][528]
    const float* __restrict__ Whr,     // float4 [16][2][512]
    const float* __restrict__ Whqr,    // float4 [16][2][16]
    const float* __restrict__ hx0, const float* __restrict__ cx0,
    float* __restrict__ stateH, float* __restrict__ stateC,
    const float* __restrict__ Wq, const float* __restrict__ bq,
    const float* __restrict__ thf, const float* __restrict__ thi,
    const float* __restrict__ thg, const float* __restrict__ tho,
    float* __restrict__ out, int t0, int TC)
{
    __shared__ __align__(16) float hL[2][HH];
    __shared__ float P[2][2][512];            // [row][kh][col] — lane-consecutive
    __shared__ __align__(16) float EZ[2][4][4];
    __shared__ float WqT[4][HH];
    __shared__ float bqL[HH];
    __shared__ float thL[4][4];   // [gate]{cos th0, cos th1, cos th2, th3(raw)}

    const int tid  = threadIdx.x;
    const int row0 = blockIdx.x * 2;
    const int col  = tid & 511;      // 0..511
    const int kh   = tid >> 9;       // wave-uniform: waves 0-7 kh=0, 8-15 kh=1

    // ---- Wh main weights into registers (coalesced: lanes = consecutive cols) ----
    const float4* Wp = (const float4*)Whr;
    const int wbase = kh * 512 + col;        // + j*1024
    float4 w00 = Wp[wbase],          w01 = Wp[wbase + 1024],  w02 = Wp[wbase + 2048],  w03 = Wp[wbase + 3072];
    float4 w04 = Wp[wbase + 4096],   w05 = Wp[wbase + 5120],  w06 = Wp[wbase + 6144],  w07 = Wp[wbase + 7168];
    float4 w08 = Wp[wbase + 8192],   w09 = Wp[wbase + 9216],  w10 = Wp[wbase + 10240], w11 = Wp[wbase + 11264];
    float4 w12 = Wp[wbase + 12288],  w13 = Wp[wbase + 13312], w14 = Wp[wbase + 14336], w15 = Wp[wbase + 15360];
    PIN4(w00); PIN4(w01); PIN4(w02); PIN4(w03);
    PIN4(w04); PIN4(w05); PIN4(w06); PIN4(w07);
    PIN4(w08); PIN4(w09); PIN4(w10); PIN4(w11);
    PIN4(w12); PIN4(w13); PIN4(w14); PIN4(w15);

    // ---- q-angle weights: wave 15, lanes 32..63 (tid 992..1023) ----
    float4 q00 = {}, q01 = {}, q02 = {}, q03 = {}, q04 = {}, q05 = {}, q06 = {}, q07 = {};
    float4 q08 = {}, q09 = {}, q10 = {}, q11 = {}, q12 = {}, q13 = {}, q14 = {}, q15 = {};
    if (tid >= 992) {
        int qlane = tid - 992, qc = qlane >> 1, qkh = qlane & 1;
        const float4* Qp = (const float4*)Whqr;
        const int qbase = qkh * 16 + qc;     // + j*32
        q00 = Qp[qbase];        q01 = Qp[qbase + 32];  q02 = Qp[qbase + 64];  q03 = Qp[qbase + 96];
        q04 = Qp[qbase + 128];  q05 = Qp[qbase + 160]; q06 = Qp[qbase + 192]; q07 = Qp[qbase + 224];
        q08 = Qp[qbase + 256];  q09 = Qp[qbase + 288]; q10 = Qp[qbase + 320]; q11 = Qp[qbase + 352];
        q12 = Qp[qbase + 384];  q13 = Qp[qbase + 416]; q14 = Qp[qbase + 448]; q15 = Qp[qbase + 480];
    }

    if (tid < HH) {
        bqL[tid] = bq[tid];
        WqT[0][tid] = Wq[tid * 4 + 0]; WqT[1][tid] = Wq[tid * 4 + 1];
        WqT[2][tid] = Wq[tid * 4 + 2]; WqT[3][tid] = Wq[tid * 4 + 3];
    }
    if (tid < 16) {
        int g = tid >> 2, w = tid & 3;
        const float* thp = (g == 0) ? thf : (g == 1) ? thi : (g == 2) ? thg : tho;
        thL[g][w] = (w == 3) ? thp[3] : cosf(thp[w]);
    }
    float cxr = 0.f;
    if (tid < 256) {
        int r = tid >> 7, h = tid & 127;
        const float* hs = (t0 == 0) ? hx0 : stateH;
        const float* cs = (t0 == 0) ? cx0 : stateC;
        hL[r][h] = hs[(size_t)(row0 + r) * HH + h];
        cxr      = cs[(size_t)(row0 + r) * HH + h];
    }
    __syncthreads();

    for (int tc = 0; tc < TC; ++tc) {
        const float* zrow = Zx + ((size_t)tc * BB + row0) * NCOL;
        // prefetch Zx (hidden under GEMM)
        float zc0 = 0, zc1 = 0, zc2 = 0, zc3 = 0;
        if (tid < 256) {
            int r = tid >> 7, h = tid & 127;
            const float* zp = zrow + (size_t)r * NCOL + h;
            zc0 = zp[0]; zc1 = zp[128]; zc2 = zp[256]; zc3 = zp[384];
        }
        float zq0 = 0, zq1 = 0;
        if (tid >= 992) {
            int qc = (tid - 992) >> 1;
            zq0 = zrow[512 + qc];
            zq1 = zrow[NCOL + 512 + qc];
        }

        // ---- h-GEMM: (col, kh) partial dot, both rows; h-reads are wave-broadcast ----
        {
            const float4* h0p = (const float4*)&hL[0][kh << 6];
            const float4* h1p = (const float4*)&hL[1][kh << 6];
            float s0a = 0, s0b = 0, s1a = 0, s1b = 0;
            #define GSTEP(J, WA, WB) { \
                float4 xa = h0p[J], xb = h0p[(J) + 1]; \
                float4 ya = h1p[J], yb = h1p[(J) + 1]; \
                FMA4(s0a, WA, xa); FMA4(s0b, WB, xb); \
                FMA4(s1a, WA, ya); FMA4(s1b, WB, yb); }
            GSTEP(0,  w00, w01) GSTEP(2,  w02, w03)
            GSTEP(4,  w04, w05) GSTEP(6,  w06, w07)
            GSTEP(8,  w08, w09) GSTEP(10, w10, w11)
            GSTEP(12, w12, w13) GSTEP(14, w14, w15)
            #undef GSTEP
            P[0][kh][col] = s0a + s0b;
            P[1][kh][col] = s1a + s1b;
        }

        // ---- wave15: q-dots + closed-form E factors via shuffles ----
        if (tid >= 992) {
            int qlane = tid - 992, qc = qlane >> 1, qkh = qlane & 1;
            const float4* hq0 = (const float4*)&hL[0][qkh << 6];
            const float4* hq1 = (const float4*)&hL[1][qkh << 6];
            float t0a = 0, t0b = 0, t1a = 0, t1b = 0;
            #define QSTEP(J, QA, QB) { \
                float4 xa = hq0[J], xb = hq0[(J) + 1]; \
                float4 ya = hq1[J], yb = hq1[(J) + 1]; \
                FMA4(t0a, QA, xa); FMA4(t0b, QB, xb); \
                FMA4(t1a, QA, ya); FMA4(t1b, QB, yb); }
            QSTEP(0,  q00, q01) QSTEP(2,  q02, q03)
            QSTEP(4,  q04, q05) QSTEP(6,  q06, q07)
            QSTEP(8,  q08, q09) QSTEP(10, q10, q11)
            QSTEP(12, q12, q13) QSTEP(14, q14, q15)
            #undef QSTEP
            float p0 = t0a + t0b, p1 = t1a + t1b;
            float a0 = zq0 + p0 + __shfl_xor(p0, 1, 64);   // full angle, row 0
            float a1 = zq1 + p1 + __shfl_xor(p1, 1, 64);   // row 1
            float cR0 = __cosf(a0), cR1 = __cosf(a1);
            int g = qc >> 2, w = qc & 3;
            int base = 32 + 8 * g;                         // lane of wire 0 of this gate
            float c00 = __shfl(cR0, base, 64),     c01 = __shfl(cR1, base, 64);
            float c10 = __shfl(cR0, base + 2, 64), c11 = __shfl(cR1, base + 2, 64);
            float c20 = __shfl(cR0, base + 4, 64), c21 = __shfl(cR1, base + 4, 64);
            float pb0 = 1.f, pb1 = 1.f, own0 = cR0, own1 = cR1, coef;
            if (w >= 1) { pb0 *= c00; pb1 *= c01; }
            if (w >= 2) { pb0 *= c10; pb1 *= c11; }
            if (w == 3) {
                pb0 *= c20; pb1 *= c21;
                own0 = __cosf(a0 + thL[g][3]); own1 = __cosf(a1 + thL[g][3]);
                coef = 1.f;
            } else coef = thL[g][w];
            if (qkh == 0) {
                EZ[0][g][w] = coef * pb0 * own0;
                EZ[1][g][w] = coef * pb1 * own1;
            }
        }
        __syncthreads();

        // ---- cell update ----
        if (tid < 256) {
            int r = tid >> 7, h = tid & 127;
            float pf = zc0 + P[r][0][h]       + P[r][1][h];
            float pi = zc1 + P[r][0][128 + h] + P[r][1][128 + h];
            float pg = zc2 + P[r][0][256 + h] + P[r][1][256 + h];
            float po = zc3 + P[r][0][384 + h] + P[r][1][384 + h];
            float wq0 = WqT[0][h], wq1 = WqT[1][h], wq2 = WqT[2][h], wq3 = WqT[3][h];
            float bb = bqL[h];
            float4 Ef = *(const float4*)&EZ[r][0][0];
            float4 Ei = *(const float4*)&EZ[r][1][0];
            float4 Eg = *(const float4*)&EZ[r][2][0];
            float4 Eo = *(const float4*)&EZ[r][3][0];
            float qf = fmaf(Ef.x, wq0, fmaf(Ef.y, wq1, fmaf(Ef.z, wq2, fmaf(Ef.w, wq3, bb))));
            float qi = fmaf(Ei.x, wq0, fmaf(Ei.y, wq1, fmaf(Ei.z, wq2, fmaf(Ei.w, wq3, bb))));
            float qg = fmaf(Eg.x, wq0, fmaf(Eg.y, wq1, fmaf(Eg.z, wq2, fmaf(Eg.w, wq3, bb))));
            float qo = fmaf(Eo.x, wq0, fmaf(Eo.y, wq1, fmaf(Eo.z, wq2, fmaf(Eo.w, wq3, bb))));
            float f  = sigm(pf)   + sigm(qf);
            float ii = sigm(pi)   + sigm(qi);
            float gg = tanh_f(pg) + tanh_f(qg);
            float oo = sigm(po)   + sigm(qo);
            float cn = fmaf(f, cxr, ii * gg);
            cxr = cn;
            float hn = oo * tanh_f(cn);
            hL[r][h] = hn;
            out[((size_t)(t0 + tc) * BB + row0 + r) * HH + h] = hn;
        }
        __syncthreads();
    }

    if (tid < 256) {
        int r = tid >> 7, h = tid & 127;
        stateH[(size_t)(row0 + r) * HH + h] = hL[r][h];
        stateC[(size_t)(row0 + r) * HH + h] = cxr;
        if (t0 + TC == TT) {
            size_t base = (size_t)TT * BB * HH;
            out[base + (size_t)(row0 + r) * HH + h]                   = hL[r][h];
            out[base + (size_t)BB * HH + (size_t)(row0 + r) * HH + h] = cxr;
        }
    }
}

extern "C" void kernel_launch(void* const* d_in, const int* in_sizes, int n_in,
                              void* d_out, int out_size, void* d_ws, size_t ws_size,
                              hipStream_t stream) {
    const float* X   = (const float*)d_in[0];
    const float* hx0 = (const float*)d_in[1];
    const float* cx0 = (const float*)d_in[2];
    const float* Wf  = (const float*)d_in[3];
    const float* bf  = (const float*)d_in[4];
    const float* Wfq = (const float*)d_in[5];
    const float* bfq = (const float*)d_in[6];
    const float* thf = (const float*)d_in[7];
    const float* Wi  = (const float*)d_in[8];
    const float* bi  = (const float*)d_in[9];
    const float* Wiq = (const float*)d_in[10];
    const float* biq = (const float*)d_in[11];
    const float* thi = (const float*)d_in[12];
    const float* Wg  = (const float*)d_in[13];
    const float* bg  = (const float*)d_in[14];
    const float* Wgq = (const float*)d_in[15];
    const float* bgq = (const float*)d_in[16];
    const float* thg = (const float*)d_in[17];
    const float* Wo  = (const float*)d_in[18];
    const float* bo  = (const float*)d_in[19];
    const float* Woq = (const float*)d_in[20];
    const float* boq = (const float*)d_in[21];
    const float* tho = (const float*)d_in[22];
    const float* Wq  = (const float*)d_in[23];
    const float* bq  = (const float*)d_in[24];

    float* ws = (float*)d_ws;
    float* Wxp    = ws;                         // 528*128
    float* Whr    = Wxp + 528 * 128;            // 16*2*512*4 = 65536
    float* Whqr   = Whr + 65536;                // 16*2*16*4 = 2048
    float* bcatp  = Whqr + 2048;                // 576
    float* stateH = bcatp + NCPAD;              // 65536
    float* stateC = stateH + 512 * 128;         // 65536
    float* Zxb    = stateC + 512 * 128;

    size_t fixed_bytes = (size_t)(Zxb - ws) * sizeof(float);
    int TC = 256;
    while (TC > 4 && fixed_bytes + (size_t)TC * 512 * NCOL * 4 > ws_size) TC >>= 1;

    pack_weights<<<(NCOL * KK + 255) / 256, 256, 0, stream>>>(
        Wf, bf, Wfq, bfq, Wi, bi, Wiq, biq, Wg, bg, Wgq, bgq, Wo, bo, Woq, boq,
        Wxp, Whr, Whqr, bcatp);

    for (int t0 = 0; t0 < TT; t0 += TC) {
        xgemm<<<dim3(TC * 512 / P1_BM, NCPAD / P1_BN), 256, 0, stream>>>(
            X + (size_t)t0 * BB * DD, Wxp, bcatp, Zxb);
        qlstm_rec<<<256, 1024, 0, stream>>>(
            Zxb, Whr, Whqr, hx0, cx0, stateH, stateC, Wq, bq,
            thf, thi, thg, tho, (float*)d_out, t0, TC);
    }
}

// Round 6
// 1686.107 us; speedup vs baseline: 1.9799x; 1.9799x over previous
//
#include <hip/hip_runtime.h>
#include <cmath>

#define TT 256
#define BB 512
#define DD 128
#define HH 128
#define NCOL 528   // 4*H + 16 quantum-angle cols
#define KK 256
#define NCPAD 576  // 9 * 64

// ---------------- weight pack ----------------
// Wxp[528][128]                     : x-half row-major (xgemm staging)
// Whr2 float4[(ci*4+k4)*512 + t]    : h-half main cols, laid out for rec's per-thread
//                                     (t = (c>>3)*8 + (kk>>4)) coalesced f4 loads
// Whql[16][128]                     : h-half quantum cols (staged to LDS in rec)
// bcat[576]
__global__ __launch_bounds__(256) void pack_weights(
    const float* __restrict__ Wf, const float* __restrict__ bf,
    const float* __restrict__ Wfq, const float* __restrict__ bfq,
    const float* __restrict__ Wi, const float* __restrict__ bi,
    const float* __restrict__ Wiq, const float* __restrict__ biq,
    const float* __restrict__ Wg, const float* __restrict__ bg,
    const float* __restrict__ Wgq, const float* __restrict__ bgq,
    const float* __restrict__ Wo, const float* __restrict__ bo,
    const float* __restrict__ Woq, const float* __restrict__ boq,
    float* __restrict__ Wxp, float* __restrict__ Whr2,
    float* __restrict__ Whql, float* __restrict__ bcat)
{
    int idx = blockIdx.x * blockDim.x + threadIdx.x;
    if (idx < NCOL * KK) {
        int c = idx >> 8, k = idx & 255;
        const float* srcW; int cl;
        if (c < 512) { int g = c >> 7; cl = c & 127;
            srcW = (g == 0) ? Wf : (g == 1) ? Wi : (g == 2) ? Wg : Wo; }
        else { int g = (c - 512) >> 2; cl = (c - 512) & 3;
            srcW = (g == 0) ? Wfq : (g == 1) ? Wiq : (g == 2) ? Wgq : Woq; }
        float v = srcW[(size_t)cl * KK + k];
        if (k < 128) Wxp[(size_t)c * 128 + k] = v;
        else {
            int kk = k - 128;
            if (c < 512) {
                int t  = ((c >> 3) << 3) | (kk >> 4);   // rec thread id
                int j  = ((c & 7) << 2) | ((kk >> 2) & 3);
                int e  = kk & 3;
                Whr2[((size_t)j * 512 + t) * 4 + e] = v;
            } else {
                Whql[(size_t)(c - 512) * 128 + kk] = v;
            }
        }
    }
    if (idx < NCPAD) {
        float b = 0.f;
        int c = idx;
        if (c < 512) { int g = c >> 7; int cl = c & 127;
            b = (g == 0) ? bf[cl] : (g == 1) ? bi[cl] : (g == 2) ? bg[cl] : bo[cl]; }
        else if (c < NCOL) { int g = (c - 512) >> 2; int cl = (c - 512) & 3;
            b = (g == 0) ? bfq[cl] : (g == 1) ? biq[cl] : (g == 2) ? bgq[cl] : boq[cl]; }
        bcat[c] = b;
    }
}

// ---------------- phase 1: Zx = X @ Wx^T + bcat  (M x 528, K=128) ----------------
#define P1_BM 128
#define P1_BN 64
#define ATP 132
#define BTP 68
__global__ __launch_bounds__(256, 3) void xgemm(
    const float* __restrict__ X, const float* __restrict__ Wxp,
    const float* __restrict__ bcat, float* __restrict__ Zx)
{
    __shared__ float At[64][ATP];
    __shared__ float Bt[64][BTP];
    const int tid = threadIdx.x;
    const int m0 = blockIdx.x * P1_BM;
    const int c0 = blockIdx.y * P1_BN;
    const int tm = tid >> 3;
    const int tn = tid & 7;
    float acc[4][8] = {};

    for (int khf = 0; khf < 2; ++khf) {
        #pragma unroll
        for (int j = 0; j < 8; ++j) {
            int fidx = tid + 256 * j;
            int m = fidx >> 4, k4 = (fidx & 15) * 4;
            float4 v = *(const float4*)(X + (size_t)(m0 + m) * 128 + khf * 64 + k4);
            At[k4 + 0][m] = v.x; At[k4 + 1][m] = v.y; At[k4 + 2][m] = v.z; At[k4 + 3][m] = v.w;
        }
        #pragma unroll
        for (int j = 0; j < 4; ++j) {
            int fidx = tid + 256 * j;
            int c = fidx >> 4, k4 = (fidx & 15) * 4;
            int cg = c0 + c;
            float4 v = make_float4(0.f, 0.f, 0.f, 0.f);
            if (cg < NCOL) v = *(const float4*)(Wxp + (size_t)cg * 128 + khf * 64 + k4);
            Bt[k4 + 0][c] = v.x; Bt[k4 + 1][c] = v.y; Bt[k4 + 2][c] = v.z; Bt[k4 + 3][c] = v.w;
        }
        __syncthreads();
        #pragma unroll 4
        for (int k = 0; k < 64; ++k) {
            float4 a  = *(const float4*)&At[k][tm * 4];
            float4 b0 = *(const float4*)&Bt[k][tn * 8];
            float4 b1 = *(const float4*)&Bt[k][tn * 8 + 4];
            float av[4] = {a.x, a.y, a.z, a.w};
            float bv[8] = {b0.x, b0.y, b0.z, b0.w, b1.x, b1.y, b1.z, b1.w};
            #pragma unroll
            for (int i = 0; i < 4; ++i)
                #pragma unroll
                for (int j = 0; j < 8; ++j)
                    acc[i][j] = fmaf(av[i], bv[j], acc[i][j]);
        }
        __syncthreads();
    }
    int c = c0 + tn * 8;
    if (c < NCOL) {
        float4 ba = *(const float4*)(bcat + c);
        float4 bb = *(const float4*)(bcat + c + 4);
        #pragma unroll
        for (int i = 0; i < 4; ++i) {
            int m = m0 + tm * 4 + i;
            float4 o0, o1;
            o0.x = acc[i][0] + ba.x; o0.y = acc[i][1] + ba.y;
            o0.z = acc[i][2] + ba.z; o0.w = acc[i][3] + ba.w;
            o1.x = acc[i][4] + bb.x; o1.y = acc[i][5] + bb.y;
            o1.z = acc[i][6] + bb.z; o1.w = acc[i][7] + bb.w;
            *(float4*)(Zx + (size_t)m * NCOL + c)     = o0;
            *(float4*)(Zx + (size_t)m * NCOL + c + 4) = o1;
        }
    }
}

// ---------------- phase 2: recurrence ----------------
__device__ __forceinline__ float sigm(float x) { return 1.0f / (1.0f + __expf(-x)); }
__device__ __forceinline__ float tanh_f(float x) {
    float e = __expf(2.f * x);
    return 1.f - 2.f / (e + 1.f);
}

// macro params must NOT be named x/y/z/w
#define FMA4(acc, Wv, Xv) acc = fmaf((Wv).x, (Xv).x, fmaf((Wv).y, (Xv).y, fmaf((Wv).z, (Xv).z, fmaf((Wv).w, (Xv).w, (acc)))))
#define PIN4(Wv) asm volatile("" : "+v"((Wv).x), "+v"((Wv).y), "+v"((Wv).z), "+v"((Wv).w))

// skewed h index: bank-conflict-free reads for the 8 k-segments
__device__ __forceinline__ int hsk(int k) { return k + 4 * (k >> 4); }  // max 155

// 512 threads, 2 waves/SIMD -> 256-VGPR budget; weights (128 VGPR) stay resident.
__global__ __launch_bounds__(512, 2) void qlstm_rec(
    const float* __restrict__ Zx,      // [TC][512][528]
    const float* __restrict__ Whr2,    // float4 [32][512]
    const float* __restrict__ Whql,    // [16][128]
    const float* __restrict__ hx0, const float* __restrict__ cx0,
    float* __restrict__ stateH, float* __restrict__ stateC,
    const float* __restrict__ Wq, const float* __restrict__ bq,
    const float* __restrict__ thf, const float* __restrict__ thi,
    const float* __restrict__ thg, const float* __restrict__ tho,
    float* __restrict__ out, int t0, int TC)
{
    __shared__ __align__(16) float hL[2][160];     // skewed
    __shared__ float S[2][512];
    __shared__ __align__(16) float WhqL[16][132];
    __shared__ float Pq[2][16];
    __shared__ float zqS[2][16];
    __shared__ float WqT[4][HH];
    __shared__ float bqL[HH];
    __shared__ float thL[4][4];   // [gate]{cos th0, cos th1, cos th2, th3(raw)}

    const int tid  = threadIdx.x;
    const int row0 = blockIdx.x * 2;
    const int ks   = tid & 7;        // k-segment (16 k each)
    const int c8   = tid >> 3;       // col group: cols c8*8 .. c8*8+7

    // ---- main weights into registers: 32 f4 = 128 VGPR, coalesced load ----
    float4 wv[32];
    const float4* Wp2 = (const float4*)Whr2;
    #pragma unroll
    for (int j = 0; j < 32; ++j) wv[j] = Wp2[j * 512 + tid];
    #pragma unroll
    for (int j = 0; j < 32; ++j) PIN4(wv[j]);

    // ---- stage q-col weights to LDS (padded) ----
    #pragma unroll
    for (int j = 0; j < 4; ++j) {
        int i = tid * 4 + j;         // 0..2047
        WhqL[i >> 7][i & 127] = Whql[i];
    }
    if (tid < HH) {
        bqL[tid] = bq[tid];
        WqT[0][tid] = Wq[tid * 4 + 0]; WqT[1][tid] = Wq[tid * 4 + 1];
        WqT[2][tid] = Wq[tid * 4 + 2]; WqT[3][tid] = Wq[tid * 4 + 3];
    }
    if (tid < 16) {
        int g = tid >> 2, w = tid & 3;
        const float* thp = (g == 0) ? thf : (g == 1) ? thi : (g == 2) ? thg : tho;
        thL[g][w] = (w == 3) ? thp[3] : cosf(thp[w]);
    }
    float cxr = 0.f;
    if (tid < 256) {
        int r = tid >> 7, h = tid & 127;
        const float* hs = (t0 == 0) ? hx0 : stateH;
        const float* cs = (t0 == 0) ? cx0 : stateC;
        hL[r][hsk(h)] = hs[(size_t)(row0 + r) * HH + h];
        cxr           = cs[(size_t)(row0 + r) * HH + h];
    }
    __syncthreads();

    for (int tc = 0; tc < TC; ++tc) {
        const float* zrow = Zx + ((size_t)tc * BB + row0) * NCOL;
        // prefetch Zx (latency hidden under GEMM)
        float zc0 = 0, zc1 = 0, zc2 = 0, zc3 = 0;
        if (tid < 256) {
            int r = tid >> 7, h = tid & 127;
            const float* zp = zrow + (size_t)r * NCOL + h;
            zc0 = zp[0]; zc1 = zp[128]; zc2 = zp[256]; zc3 = zp[384];
        }
        float zqv = 0;
        if (tid >= 480) {
            int i = tid - 480;       // r = i>>4, qc = i&15
            zqv = zrow[(size_t)(i >> 4) * NCOL + 512 + (i & 15)];
        }

        // ---- main GEMM: 8 cols x 16 k x 2 rows per thread ----
        float acc[2][8] = {};
        #pragma unroll
        for (int k4 = 0; k4 < 4; ++k4) {
            float4 hv0 = *(const float4*)&hL[0][20 * ks + 4 * k4];
            float4 hv1 = *(const float4*)&hL[1][20 * ks + 4 * k4];
            #pragma unroll
            for (int ci = 0; ci < 8; ++ci) {
                FMA4(acc[0][ci], wv[ci * 4 + k4], hv0);
                FMA4(acc[1][ci], wv[ci * 4 + k4], hv1);
            }
        }
        // butterfly-reduce over the 8 k-segments (same wave by construction)
        #pragma unroll
        for (int r = 0; r < 2; ++r)
            #pragma unroll
            for (int ci = 0; ci < 8; ++ci) {
                float v = acc[r][ci];
                v += __shfl_xor(v, 1, 64);
                v += __shfl_xor(v, 2, 64);
                v += __shfl_xor(v, 4, 64);
                acc[r][ci] = v;
            }
        if (ks < 2) {
            int r = ks;
            float4 o0 = make_float4(acc[r][0], acc[r][1], acc[r][2], acc[r][3]);
            float4 o1 = make_float4(acc[r][4], acc[r][5], acc[r][6], acc[r][7]);
            *(float4*)&S[r][c8 * 8]     = o0;
            *(float4*)&S[r][c8 * 8 + 4] = o1;
        }

        // ---- q-col dots: 256 micro-tasks on threads 256..511 ----
        if (tid >= 256) {
            int i = tid - 256;
            int ks8 = i & 7, rq = (i >> 3) & 1, qc = i >> 4;
            const float4* wq4 = (const float4*)&WhqL[qc][ks8 * 16];
            float qa = 0.f;
            #pragma unroll
            for (int k4 = 0; k4 < 4; ++k4) {
                float4 hv = *(const float4*)&hL[rq][20 * ks8 + 4 * k4];
                FMA4(qa, wq4[k4], hv);
            }
            qa += __shfl_xor(qa, 1, 64);
            qa += __shfl_xor(qa, 2, 64);
            qa += __shfl_xor(qa, 4, 64);
            if (ks8 == 0) Pq[rq][qc] = qa;
        }
        if (tid >= 480) {
            int i = tid - 480;
            zqS[i >> 4][i & 15] = zqv;
        }
        __syncthreads();

        // ---- cell update with closed-form quantum expectation ----
        if (tid < 256) {
            int r = tid >> 7, h = tid & 127;
            float pf = zc0 + S[r][h];
            float pi = zc1 + S[r][128 + h];
            float pg = zc2 + S[r][256 + h];
            float po = zc3 + S[r][384 + h];
            float wq0 = WqT[0][h], wq1 = WqT[1][h], wq2 = WqT[2][h], wq3 = WqT[3][h];
            float bb = bqL[h];
            float qz[4];
            #pragma unroll
            for (int g = 0; g < 4; ++g) {
                float a0 = zqS[r][g * 4 + 0] + Pq[r][g * 4 + 0];
                float a1 = zqS[r][g * 4 + 1] + Pq[r][g * 4 + 1];
                float a2 = zqS[r][g * 4 + 2] + Pq[r][g * 4 + 2];
                float a3 = zqS[r][g * 4 + 3] + Pq[r][g * 4 + 3];
                float c0 = __cosf(a0), c1 = __cosf(a1), c2 = __cosf(a2);
                float c01  = c0 * c1;
                float c012 = c01 * c2;
                float e0 = thL[g][0] * c0;
                float e1 = thL[g][1] * c01;
                float e2 = thL[g][2] * c012;
                float e3 = c012 * __cosf(a3 + thL[g][3]);
                qz[g] = fmaf(e0, wq0, fmaf(e1, wq1, fmaf(e2, wq2, fmaf(e3, wq3, bb))));
            }
            float f  = sigm(pf)   + sigm(qz[0]);
            float ii = sigm(pi)   + sigm(qz[1]);
            float gg = tanh_f(pg) + tanh_f(qz[2]);
            float oo = sigm(po)   + sigm(qz[3]);
            float cn = fmaf(f, cxr, ii * gg);
            cxr = cn;
            float hn = oo * tanh_f(cn);
            hL[r][hsk(h)] = hn;
            out[((size_t)(t0 + tc) * BB + row0 + r) * HH + h] = hn;
        }
        __syncthreads();
    }

    if (tid < 256) {
        int r = tid >> 7, h = tid & 127;
        stateH[(size_t)(row0 + r) * HH + h] = hL[r][hsk(h)];
        stateC[(size_t)(row0 + r) * HH + h] = cxr;
        if (t0 + TC == TT) {
            size_t base = (size_t)TT * BB * HH;
            out[base + (size_t)(row0 + r) * HH + h]                   = hL[r][hsk(h)];
            out[base + (size_t)BB * HH + (size_t)(row0 + r) * HH + h] = cxr;
        }
    }
}

extern "C" void kernel_launch(void* const* d_in, const int* in_sizes, int n_in,
                              void* d_out, int out_size, void* d_ws, size_t ws_size,
                              hipStream_t stream) {
    const float* X   = (const float*)d_in[0];
    const float* hx0 = (const float*)d_in[1];
    const float* cx0 = (const float*)d_in[2];
    const float* Wf  = (const float*)d_in[3];
    const float* bf  = (const float*)d_in[4];
    const float* Wfq = (const float*)d_in[5];
    const float* bfq = (const float*)d_in[6];
    const float* thf = (const float*)d_in[7];
    const float* Wi  = (const float*)d_in[8];
    const float* bi  = (const float*)d_in[9];
    const float* Wiq = (const float*)d_in[10];
    const float* biq = (const float*)d_in[11];
    const float* thi = (const float*)d_in[12];
    const float* Wg  = (const float*)d_in[13];
    const float* bg  = (const float*)d_in[14];
    const float* Wgq = (const float*)d_in[15];
    const float* bgq = (const float*)d_in[16];
    const float* thg = (const float*)d_in[17];
    const float* Wo  = (const float*)d_in[18];
    const float* bo  = (const float*)d_in[19];
    const float* Woq = (const float*)d_in[20];
    const float* boq = (const float*)d_in[21];
    const float* tho = (const float*)d_in[22];
    const float* Wq  = (const float*)d_in[23];
    const float* bq  = (const float*)d_in[24];

    float* ws = (float*)d_ws;
    float* Wxp    = ws;                         // 528*128 = 67584
    float* Whr2   = Wxp + 528 * 128;            // 32*512*4 = 65536
    float* Whql   = Whr2 + 65536;               // 16*128 = 2048
    float* bcatp  = Whql + 2048;                // 576
    float* stateH = bcatp + NCPAD;              // 65536
    float* stateC = stateH + 512 * 128;         // 65536
    float* Zxb    = stateC + 512 * 128;

    size_t fixed_bytes = (size_t)(Zxb - ws) * sizeof(float);
    int TC = 256;
    while (TC > 4 && fixed_bytes + (size_t)TC * 512 * NCOL * 4 > ws_size) TC >>= 1;

    pack_weights<<<(NCOL * KK + 255) / 256, 256, 0, stream>>>(
        Wf, bf, Wfq, bfq, Wi, bi, Wiq, biq, Wg, bg, Wgq, bgq, Wo, bo, Woq, boq,
        Wxp, Whr2, Whql, bcatp);

    for (int t0 = 0; t0 < TT; t0 += TC) {
        xgemm<<<dim3(TC * 512 / P1_BM, NCPAD / P1_BN), 256, 0, stream>>>(
            X + (size_t)t0 * BB * DD, Wxp, bcatp, Zxb);
        qlstm_rec<<<256, 512, 0, stream>>>(
            Zxb, Whr2, Whql, hx0, cx0, stateH, stateC, Wq, bq,
            thf, thi, thg, tho, (float*)d_out, t0, TC);
    }
}

// Round 7
// 933.272 us; speedup vs baseline: 3.5769x; 1.8067x over previous
//
#include <hip/hip_runtime.h>
#include <cmath>

#define TT 256
#define BB 512
#define DD 128
#define HH 128
#define NCOL 528   // 4*H + 16 quantum-angle cols
#define KK 256
#define NCPAD 576  // 9 * 64

// ---------------- weight pack ----------------
// Wxp[528][128]                  : x-half row-major (xgemm staging)
// Whr2 float4[j][t]  (j=ci*4+k4) : h-half main cols; thread t=c8*8+ks owns cols
//                                  {gate*128 + 2*c8 + b : ci=gate*2+b}, k-seg ks
// Whql[16][128]                  : h-half quantum cols (staged to LDS in rec)
// bcat[576]
__global__ __launch_bounds__(256) void pack_weights(
    const float* __restrict__ Wf, const float* __restrict__ bf,
    const float* __restrict__ Wfq, const float* __restrict__ bfq,
    const float* __restrict__ Wi, const float* __restrict__ bi,
    const float* __restrict__ Wiq, const float* __restrict__ biq,
    const float* __restrict__ Wg, const float* __restrict__ bg,
    const float* __restrict__ Wgq, const float* __restrict__ bgq,
    const float* __restrict__ Wo, const float* __restrict__ bo,
    const float* __restrict__ Woq, const float* __restrict__ boq,
    float* __restrict__ Wxp, float* __restrict__ Whr2,
    float* __restrict__ Whql, float* __restrict__ bcat)
{
    int idx = blockIdx.x * blockDim.x + threadIdx.x;
    if (idx < NCOL * KK) {
        int c = idx >> 8, k = idx & 255;
        const float* srcW; int cl;
        if (c < 512) { int g = c >> 7; cl = c & 127;
            srcW = (g == 0) ? Wf : (g == 1) ? Wi : (g == 2) ? Wg : Wo; }
        else { int g = (c - 512) >> 2; cl = (c - 512) & 3;
            srcW = (g == 0) ? Wfq : (g == 1) ? Wiq : (g == 2) ? Wgq : Woq; }
        float v = srcW[(size_t)cl * KK + k];
        if (k < 128) Wxp[(size_t)c * 128 + k] = v;
        else {
            int kk = k - 128;
            if (c < 512) {
                int gate = c >> 7, hcol = c & 127;
                int c8p = hcol >> 1, bp = hcol & 1;
                int ci = gate * 2 + bp;
                int t  = c8p * 8 + (kk >> 4);
                int j  = ci * 4 + ((kk >> 2) & 3);
                Whr2[((size_t)j * 512 + t) * 4 + (kk & 3)] = v;
            } else {
                Whql[(size_t)(c - 512) * 128 + kk] = v;
            }
        }
    }
    if (idx < NCPAD) {
        float b = 0.f;
        int c = idx;
        if (c < 512) { int g = c >> 7; int cl = c & 127;
            b = (g == 0) ? bf[cl] : (g == 1) ? bi[cl] : (g == 2) ? bg[cl] : bo[cl]; }
        else if (c < NCOL) { int g = (c - 512) >> 2; int cl = (c - 512) & 3;
            b = (g == 0) ? bfq[cl] : (g == 1) ? biq[cl] : (g == 2) ? bgq[cl] : boq[cl]; }
        bcat[c] = b;
    }
}

// ---------------- phase 1: Zx = X @ Wx^T + bcat  (M x 528, K=128) ----------------
#define P1_BM 128
#define P1_BN 64
#define ATP 132
#define BTP 68
__global__ __launch_bounds__(256, 3) void xgemm(
    const float* __restrict__ X, const float* __restrict__ Wxp,
    const float* __restrict__ bcat, float* __restrict__ Zx)
{
    __shared__ float At[64][ATP];
    __shared__ float Bt[64][BTP];
    const int tid = threadIdx.x;
    const int m0 = blockIdx.x * P1_BM;
    const int c0 = blockIdx.y * P1_BN;
    const int tm = tid >> 3;
    const int tn = tid & 7;
    float acc[4][8] = {};

    for (int khf = 0; khf < 2; ++khf) {
        #pragma unroll
        for (int j = 0; j < 8; ++j) {
            int fidx = tid + 256 * j;
            int m = fidx >> 4, k4 = (fidx & 15) * 4;
            float4 v = *(const float4*)(X + (size_t)(m0 + m) * 128 + khf * 64 + k4);
            At[k4 + 0][m] = v.x; At[k4 + 1][m] = v.y; At[k4 + 2][m] = v.z; At[k4 + 3][m] = v.w;
        }
        #pragma unroll
        for (int j = 0; j < 4; ++j) {
            int fidx = tid + 256 * j;
            int c = fidx >> 4, k4 = (fidx & 15) * 4;
            int cg = c0 + c;
            float4 v = make_float4(0.f, 0.f, 0.f, 0.f);
            if (cg < NCOL) v = *(const float4*)(Wxp + (size_t)cg * 128 + khf * 64 + k4);
            Bt[k4 + 0][c] = v.x; Bt[k4 + 1][c] = v.y; Bt[k4 + 2][c] = v.z; Bt[k4 + 3][c] = v.w;
        }
        __syncthreads();
        #pragma unroll 4
        for (int k = 0; k < 64; ++k) {
            float4 a  = *(const float4*)&At[k][tm * 4];
            float4 b0 = *(const float4*)&Bt[k][tn * 8];
            float4 b1 = *(const float4*)&Bt[k][tn * 8 + 4];
            float av[4] = {a.x, a.y, a.z, a.w};
            float bv[8] = {b0.x, b0.y, b0.z, b0.w, b1.x, b1.y, b1.z, b1.w};
            #pragma unroll
            for (int i = 0; i < 4; ++i)
                #pragma unroll
                for (int j = 0; j < 8; ++j)
                    acc[i][j] = fmaf(av[i], bv[j], acc[i][j]);
        }
        __syncthreads();
    }
    int c = c0 + tn * 8;
    if (c < NCOL) {
        float4 ba = *(const float4*)(bcat + c);
        float4 bb = *(const float4*)(bcat + c + 4);
        #pragma unroll
        for (int i = 0; i < 4; ++i) {
            int m = m0 + tm * 4 + i;
            float4 o0, o1;
            o0.x = acc[i][0] + ba.x; o0.y = acc[i][1] + ba.y;
            o0.z = acc[i][2] + ba.z; o0.w = acc[i][3] + ba.w;
            o1.x = acc[i][4] + bb.x; o1.y = acc[i][5] + bb.y;
            o1.z = acc[i][6] + bb.z; o1.w = acc[i][7] + bb.w;
            *(float4*)(Zx + (size_t)m * NCOL + c)     = o0;
            *(float4*)(Zx + (size_t)m * NCOL + c + 4) = o1;
        }
    }
}

// ---------------- phase 2: recurrence ----------------
__device__ __forceinline__ float sigm(float x) { return 1.0f / (1.0f + __expf(-x)); }
__device__ __forceinline__ float tanh_f(float x) {
    float e = __expf(2.f * x);
    return 1.f - 2.f / (e + 1.f);
}

// macro params must NOT be named x/y/z/w
#define FMA4(acc, Wv, Xv) acc = fmaf((Wv).x, (Xv).x, fmaf((Wv).y, (Xv).y, fmaf((Wv).z, (Xv).z, fmaf((Wv).w, (Xv).w, (acc)))))
#define PIN4(Wv) asm volatile("" : "+v"((Wv).x), "+v"((Wv).y), "+v"((Wv).z), "+v"((Wv).w))

// skewed h index: k-segment reads land on all 32 banks
__device__ __forceinline__ int hsk(int k) { return k + 4 * (k >> 4); }  // max 155

// 512 threads; waves_per_eu(2,2): 256-VGPR cap, no occupancy-greed spilling.
__global__ __launch_bounds__(512)
__attribute__((amdgpu_waves_per_eu(2, 2)))
void qlstm_rec(
    const float* __restrict__ Zx,      // [TC][512][528]
    const float* __restrict__ Whr2,    // float4 [32][512]
    const float* __restrict__ Whql,    // [16][128]
    const float* __restrict__ hx0, const float* __restrict__ cx0,
    float* __restrict__ stateH, float* __restrict__ stateC,
    const float* __restrict__ Wq, const float* __restrict__ bq,
    const float* __restrict__ thf, const float* __restrict__ thi,
    const float* __restrict__ thg, const float* __restrict__ tho,
    float* __restrict__ out, int t0, int TC)
{
    __shared__ __align__(16) float hL[2][160];     // skewed
    __shared__ __align__(16) float WhqL[16][132];
    __shared__ __align__(16) float EZ[2][4][4];

    const int tid  = threadIdx.x;
    const int row0 = blockIdx.x * 2;
    const int ks   = tid & 7;        // k-segment (16 k each)
    const int c8   = tid >> 3;       // h-pair index
    const int lane = tid & 63;

    // ---- main weights into registers: 32 f4 = 128 VGPR, coalesced load ----
    float4 wv[32];
    const float4* Wp2 = (const float4*)Whr2;
    #pragma unroll
    for (int j = 0; j < 32; ++j) wv[j] = Wp2[j * 512 + tid];
    #pragma unroll
    for (int j = 0; j < 32; ++j) PIN4(wv[j]);

    // ---- stage q-col weights to LDS (padded) ----
    #pragma unroll
    for (int j = 0; j < 4; ++j) {
        int i = tid * 4 + j;         // 0..2047
        WhqL[i >> 7][i & 127] = Whql[i];
    }

    // ---- per-thread invariants ----
    const bool isCell = (ks < 4);
    int r = 0, b = 0, h = 0;
    float4 wqv = make_float4(0.f, 0.f, 0.f, 0.f);
    float bb = 0.f, cxr = 0.f;
    if (isCell) {
        r = ks & 1; b = (ks >> 1) & 1; h = 2 * c8 + b;
        wqv = *(const float4*)(Wq + h * 4);
        bb  = bq[h];
    }
    int qc = 0, rq = 0, kseg = 0, qw = 0, qg = 0;
    float qcoef = 1.f, qth3 = 0.f;
    if (tid < 256) {
        qc = tid >> 4; rq = (tid >> 3) & 1; kseg = tid & 7;
        qg = qc >> 2;  qw = qc & 3;
        const float* thp = (qg == 0) ? thf : (qg == 1) ? thi : (qg == 2) ? thg : tho;
        qcoef = (qw < 3) ? cosf(thp[qw]) : 1.f;
        qth3  = thp[3];
    }
    if (isCell) {
        const float* hs = (t0 == 0) ? hx0 : stateH;
        const float* cs = (t0 == 0) ? cx0 : stateC;
        hL[r][hsk(h)] = hs[(size_t)(row0 + r) * HH + h];
        cxr           = cs[(size_t)(row0 + r) * HH + h];
    }
    __syncthreads();

    for (int tc = 0; tc < TC; ++tc) {
        const float* zrow = Zx + ((size_t)tc * BB + row0) * NCOL;
        // prefetch (latency hidden under GEMM)
        float zc0 = 0, zc1 = 0, zc2 = 0, zc3 = 0, zqv = 0;
        if (isCell) {
            const float* zp = zrow + (size_t)r * NCOL + h;
            zc0 = zp[0]; zc1 = zp[128]; zc2 = zp[256]; zc3 = zp[384];
        }
        if (tid < 256) zqv = zrow[(size_t)rq * NCOL + 512 + qc];

        #pragma unroll
        for (int j = 0; j < 32; ++j) PIN4(wv[j]);   // anchor weights each step

        // ---- h-GEMM: 8 cols x 16 k x 2 rows per thread; q-dot fused ----
        float acc0[8] = {}, acc1[8] = {};
        float qa = 0.f;
        #pragma unroll
        for (int k4 = 0; k4 < 4; ++k4) {
            float4 hv0 = *(const float4*)&hL[0][20 * ks + 4 * k4];
            float4 hv1 = *(const float4*)&hL[1][20 * ks + 4 * k4];
            #pragma unroll
            for (int ci = 0; ci < 8; ++ci) {
                FMA4(acc0[ci], wv[ci * 4 + k4], hv0);
                FMA4(acc1[ci], wv[ci * 4 + k4], hv1);
            }
            if (tid < 256) {
                float4 wq4 = *(const float4*)&WhqL[qc][kseg * 16 + 4 * k4];
                float4 hs4;
                hs4.x = rq ? hv1.x : hv0.x; hs4.y = rq ? hv1.y : hv0.y;
                hs4.z = rq ? hv1.z : hv0.z; hs4.w = rq ? hv1.w : hv0.w;
                FMA4(qa, wq4, hs4);
            }
        }
        // butterfly allreduce over the 8 k-segments
        #pragma unroll
        for (int ci = 0; ci < 8; ++ci) {
            float v0 = acc0[ci];
            v0 += __shfl_xor(v0, 1, 64); v0 += __shfl_xor(v0, 2, 64); v0 += __shfl_xor(v0, 4, 64);
            acc0[ci] = v0;
            float v1 = acc1[ci];
            v1 += __shfl_xor(v1, 1, 64); v1 += __shfl_xor(v1, 2, 64); v1 += __shfl_xor(v1, 4, 64);
            acc1[ci] = v1;
        }
        // ---- q side: finish dot, closed-form E factors, write EZ ----
        if (tid < 256) {
            qa += __shfl_xor(qa, 1, 64); qa += __shfl_xor(qa, 2, 64); qa += __shfl_xor(qa, 4, 64);
            float a  = zqv + qa;
            float c  = __cosf(a);
            float cw0 = __shfl(c, (lane & 15), 64);
            float cw1 = __shfl(c, 16 + (lane & 15), 64);
            float cw2 = __shfl(c, 32 + (lane & 15), 64);
            float own = (qw == 3) ? __cosf(a + qth3) : c;
            float prod = 1.f;
            if (qw >= 1) prod *= cw0;
            if (qw >= 2) prod *= cw1;
            if (qw == 3) prod *= cw2;
            float E = qcoef * prod * own;
            if (kseg == 0) EZ[rq][qg][qw] = E;
        }
        __syncthreads();

        // ---- fused cell update (own cols already in acc) ----
        if (isCell) {
            float m0 = r ? acc1[0] : acc0[0];
            float m1 = r ? acc1[1] : acc0[1];
            float m2 = r ? acc1[2] : acc0[2];
            float m3 = r ? acc1[3] : acc0[3];
            float m4 = r ? acc1[4] : acc0[4];
            float m5 = r ? acc1[5] : acc0[5];
            float m6 = r ? acc1[6] : acc0[6];
            float m7 = r ? acc1[7] : acc0[7];
            float pf = zc0 + (b ? m1 : m0);
            float pi = zc1 + (b ? m3 : m2);
            float pg = zc2 + (b ? m5 : m4);
            float po = zc3 + (b ? m7 : m6);
            float4 Ef = *(const float4*)&EZ[r][0][0];
            float4 Ei = *(const float4*)&EZ[r][1][0];
            float4 Eg = *(const float4*)&EZ[r][2][0];
            float4 Eo = *(const float4*)&EZ[r][3][0];
            float qf = fmaf(Ef.x, wqv.x, fmaf(Ef.y, wqv.y, fmaf(Ef.z, wqv.z, fmaf(Ef.w, wqv.w, bb))));
            float qi = fmaf(Ei.x, wqv.x, fmaf(Ei.y, wqv.y, fmaf(Ei.z, wqv.z, fmaf(Ei.w, wqv.w, bb))));
            float qg2 = fmaf(Eg.x, wqv.x, fmaf(Eg.y, wqv.y, fmaf(Eg.z, wqv.z, fmaf(Eg.w, wqv.w, bb))));
            float qo = fmaf(Eo.x, wqv.x, fmaf(Eo.y, wqv.y, fmaf(Eo.z, wqv.z, fmaf(Eo.w, wqv.w, bb))));
            float f  = sigm(pf)   + sigm(qf);
            float ii = sigm(pi)   + sigm(qi);
            float gg = tanh_f(pg) + tanh_f(qg2);
            float oo = sigm(po)   + sigm(qo);
            float cn = fmaf(f, cxr, ii * gg);
            cxr = cn;
            float hn = oo * tanh_f(cn);
            hL[r][hsk(h)] = hn;
            out[((size_t)(t0 + tc) * BB + row0 + r) * HH + h] = hn;
        }
        __syncthreads();
    }

    if (isCell) {
        float hn = hL[r][hsk(h)];
        stateH[(size_t)(row0 + r) * HH + h] = hn;
        stateC[(size_t)(row0 + r) * HH + h] = cxr;
        if (t0 + TC == TT) {
            size_t base = (size_t)TT * BB * HH;
            out[base + (size_t)(row0 + r) * HH + h]                   = hn;
            out[base + (size_t)BB * HH + (size_t)(row0 + r) * HH + h] = cxr;
        }
    }
}

extern "C" void kernel_launch(void* const* d_in, const int* in_sizes, int n_in,
                              void* d_out, int out_size, void* d_ws, size_t ws_size,
                              hipStream_t stream) {
    const float* X   = (const float*)d_in[0];
    const float* hx0 = (const float*)d_in[1];
    const float* cx0 = (const float*)d_in[2];
    const float* Wf  = (const float*)d_in[3];
    const float* bf  = (const float*)d_in[4];
    const float* Wfq = (const float*)d_in[5];
    const float* bfq = (const float*)d_in[6];
    const float* thf = (const float*)d_in[7];
    const float* Wi  = (const float*)d_in[8];
    const float* bi  = (const float*)d_in[9];
    const float* Wiq = (const float*)d_in[10];
    const float* biq = (const float*)d_in[11];
    const float* thi = (const float*)d_in[12];
    const float* Wg  = (const float*)d_in[13];
    const float* bg  = (const float*)d_in[14];
    const float* Wgq = (const float*)d_in[15];
    const float* bgq = (const float*)d_in[16];
    const float* thg = (const float*)d_in[17];
    const float* Wo  = (const float*)d_in[18];
    const float* bo  = (const float*)d_in[19];
    const float* Woq = (const float*)d_in[20];
    const float* boq = (const float*)d_in[21];
    const float* tho = (const float*)d_in[22];
    const float* Wq  = (const float*)d_in[23];
    const float* bq  = (const float*)d_in[24];

    float* ws = (float*)d_ws;
    float* Wxp    = ws;                         // 528*128 = 67584
    float* Whr2   = Wxp + 528 * 128;            // 32*512*4 = 65536
    float* Whql   = Whr2 + 65536;               // 16*128 = 2048
    float* bcatp  = Whql + 2048;                // 576
    float* stateH = bcatp + NCPAD;              // 65536
    float* stateC = stateH + 512 * 128;         // 65536
    float* Zxb    = stateC + 512 * 128;

    size_t fixed_bytes = (size_t)(Zxb - ws) * sizeof(float);
    int TC = 256;
    while (TC > 4 && fixed_bytes + (size_t)TC * 512 * NCOL * 4 > ws_size) TC >>= 1;

    pack_weights<<<(NCOL * KK + 255) / 256, 256, 0, stream>>>(
        Wf, bf, Wfq, bfq, Wi, bi, Wiq, biq, Wg, bg, Wgq, bgq, Wo, bo, Woq, boq,
        Wxp, Whr2, Whql, bcatp);

    for (int t0 = 0; t0 < TT; t0 += TC) {
        xgemm<<<dim3(TC * 512 / P1_BM, NCPAD / P1_BN), 256, 0, stream>>>(
            X + (size_t)t0 * BB * DD, Wxp, bcatp, Zxb);
        qlstm_rec<<<256, 512, 0, stream>>>(
            Zxb, Whr2, Whql, hx0, cx0, stateH, stateC, Wq, bq,
            thf, thi, thg, tho, (float*)d_out, t0, TC);
    }
}

// Round 8
// 767.936 us; speedup vs baseline: 4.3471x; 1.2153x over previous
//
#include <hip/hip_runtime.h>
#include <cmath>

#define TT 256
#define BB 512
#define DD 128
#define HH 128
#define NCOL 528   // 4*H + 16 quantum-angle cols
#define KK 256
#define NCPAD 576  // 9 * 64

// ---------------- weight pack ----------------
// Wxp[528][128]                 : x-half row-major (xgemm staging)
// Whr3 float4[j][t] (j=g*8+k4)  : h-half main cols; thread t=h*4+ks owns cols
//                                 {g*128+h, g=0..3}, k-seg ks (32 k each)
// Whql[16][128]                 : h-half quantum cols (staged to LDS in rec)
// bcat[576]
__global__ __launch_bounds__(256) void pack_weights(
    const float* __restrict__ Wf, const float* __restrict__ bf,
    const float* __restrict__ Wfq, const float* __restrict__ bfq,
    const float* __restrict__ Wi, const float* __restrict__ bi,
    const float* __restrict__ Wiq, const float* __restrict__ biq,
    const float* __restrict__ Wg, const float* __restrict__ bg,
    const float* __restrict__ Wgq, const float* __restrict__ bgq,
    const float* __restrict__ Wo, const float* __restrict__ bo,
    const float* __restrict__ Woq, const float* __restrict__ boq,
    float* __restrict__ Wxp, float* __restrict__ Whr3,
    float* __restrict__ Whql, float* __restrict__ bcat)
{
    int idx = blockIdx.x * blockDim.x + threadIdx.x;
    if (idx < NCOL * KK) {
        int c = idx >> 8, k = idx & 255;
        const float* srcW; int cl;
        if (c < 512) { int g = c >> 7; cl = c & 127;
            srcW = (g == 0) ? Wf : (g == 1) ? Wi : (g == 2) ? Wg : Wo; }
        else { int g = (c - 512) >> 2; cl = (c - 512) & 3;
            srcW = (g == 0) ? Wfq : (g == 1) ? Wiq : (g == 2) ? Wgq : Woq; }
        float v = srcW[(size_t)cl * KK + k];
        if (k < 128) Wxp[(size_t)c * 128 + k] = v;
        else {
            int kk = k - 128;
            if (c < 512) {
                int gate = c >> 7, hcol = c & 127;
                int t = hcol * 4 + (kk >> 5);
                int j = gate * 8 + ((kk >> 2) & 7);
                Whr3[((size_t)j * 512 + t) * 4 + (kk & 3)] = v;
            } else {
                Whql[(size_t)(c - 512) * 128 + kk] = v;
            }
        }
    }
    if (idx < NCPAD) {
        float b = 0.f;
        int c = idx;
        if (c < 512) { int g = c >> 7; int cl = c & 127;
            b = (g == 0) ? bf[cl] : (g == 1) ? bi[cl] : (g == 2) ? bg[cl] : bo[cl]; }
        else if (c < NCOL) { int g = (c - 512) >> 2; int cl = (c - 512) & 3;
            b = (g == 0) ? bfq[cl] : (g == 1) ? biq[cl] : (g == 2) ? bgq[cl] : boq[cl]; }
        bcat[c] = b;
    }
}

// ---------------- phase 1: Zx = X @ Wx^T + bcat  (M x 528, K=128) ----------------
#define P1_BM 128
#define P1_BN 64
#define ATP 132
#define BTP 68
__global__ __launch_bounds__(256, 3) void xgemm(
    const float* __restrict__ X, const float* __restrict__ Wxp,
    const float* __restrict__ bcat, float* __restrict__ Zx)
{
    __shared__ float At[64][ATP];
    __shared__ float Bt[64][BTP];
    const int tid = threadIdx.x;
    const int m0 = blockIdx.x * P1_BM;
    const int c0 = blockIdx.y * P1_BN;
    const int tm = tid >> 3;
    const int tn = tid & 7;
    float acc[4][8] = {};

    for (int khf = 0; khf < 2; ++khf) {
        #pragma unroll
        for (int j = 0; j < 8; ++j) {
            int fidx = tid + 256 * j;
            int m = fidx >> 4, k4 = (fidx & 15) * 4;
            float4 v = *(const float4*)(X + (size_t)(m0 + m) * 128 + khf * 64 + k4);
            At[k4 + 0][m] = v.x; At[k4 + 1][m] = v.y; At[k4 + 2][m] = v.z; At[k4 + 3][m] = v.w;
        }
        #pragma unroll
        for (int j = 0; j < 4; ++j) {
            int fidx = tid + 256 * j;
            int c = fidx >> 4, k4 = (fidx & 15) * 4;
            int cg = c0 + c;
            float4 v = make_float4(0.f, 0.f, 0.f, 0.f);
            if (cg < NCOL) v = *(const float4*)(Wxp + (size_t)cg * 128 + khf * 64 + k4);
            Bt[k4 + 0][c] = v.x; Bt[k4 + 1][c] = v.y; Bt[k4 + 2][c] = v.z; Bt[k4 + 3][c] = v.w;
        }
        __syncthreads();
        #pragma unroll 4
        for (int k = 0; k < 64; ++k) {
            float4 a  = *(const float4*)&At[k][tm * 4];
            float4 b0 = *(const float4*)&Bt[k][tn * 8];
            float4 b1 = *(const float4*)&Bt[k][tn * 8 + 4];
            float av[4] = {a.x, a.y, a.z, a.w};
            float bv[8] = {b0.x, b0.y, b0.z, b0.w, b1.x, b1.y, b1.z, b1.w};
            #pragma unroll
            for (int i = 0; i < 4; ++i)
                #pragma unroll
                for (int j = 0; j < 8; ++j)
                    acc[i][j] = fmaf(av[i], bv[j], acc[i][j]);
        }
        __syncthreads();
    }
    int c = c0 + tn * 8;
    if (c < NCOL) {
        float4 ba = *(const float4*)(bcat + c);
        float4 bb = *(const float4*)(bcat + c + 4);
        #pragma unroll
        for (int i = 0; i < 4; ++i) {
            int m = m0 + tm * 4 + i;
            float4 o0, o1;
            o0.x = acc[i][0] + ba.x; o0.y = acc[i][1] + ba.y;
            o0.z = acc[i][2] + ba.z; o0.w = acc[i][3] + ba.w;
            o1.x = acc[i][4] + bb.x; o1.y = acc[i][5] + bb.y;
            o1.z = acc[i][6] + bb.z; o1.w = acc[i][7] + bb.w;
            *(float4*)(Zx + (size_t)m * NCOL + c)     = o0;
            *(float4*)(Zx + (size_t)m * NCOL + c + 4) = o1;
        }
    }
}

// ---------------- phase 2: recurrence ----------------
__device__ __forceinline__ float sigm(float x) { return 1.0f / (1.0f + __expf(-x)); }
__device__ __forceinline__ float tanh_f(float x) {
    float e = __expf(2.f * x);
    return 1.f - 2.f / (e + 1.f);
}

// macro params must NOT be named x/y/z/w
#define FMA4(acc, Wv, Xv) acc = fmaf((Wv).x, (Xv).x, fmaf((Wv).y, (Xv).y, fmaf((Wv).z, (Xv).z, fmaf((Wv).w, (Xv).w, (acc)))))
#define PIN4(Wv) asm volatile("" : "+v"((Wv).x), "+v"((Wv).y), "+v"((Wv).z), "+v"((Wv).w))

// skewed h index: the 4 k-segments land on distinct bank quads
__device__ __forceinline__ int hsk(int k) { return k + 8 * (k >> 5); }  // max 151

// 512 threads; waves_per_eu(2,2): 256-VGPR cap, no occupancy-greed spilling.
__global__ __launch_bounds__(512)
__attribute__((amdgpu_waves_per_eu(2, 2)))
void qlstm_rec(
    const float* __restrict__ Zx,      // [TC][512][528]
    const float* __restrict__ Whr3,    // float4 [32][512]
    const float* __restrict__ Whql,    // [16][128]
    const float* __restrict__ hx0, const float* __restrict__ cx0,
    float* __restrict__ stateH, float* __restrict__ stateC,
    const float* __restrict__ Wq, const float* __restrict__ bq,
    const float* __restrict__ thf, const float* __restrict__ thi,
    const float* __restrict__ thg, const float* __restrict__ tho,
    float* __restrict__ out, int t0, int TC)
{
    __shared__ __align__(16) float hL[2][152];     // skewed
    __shared__ __align__(16) float WhqL[16][132];
    __shared__ __align__(16) float EZ[2][4][4];

    const int tid  = threadIdx.x;
    const int row0 = blockIdx.x * 2;
    const int ks   = tid & 3;        // k-segment (32 k each)
    const int h    = tid >> 2;       // 0..127: this thread's h column

    // ---- main weights into registers: 32 f4 = 128 regs, coalesced load ----
    float4 wv[32];
    const float4* Wp3 = (const float4*)Whr3;
    #pragma unroll
    for (int j = 0; j < 32; ++j) wv[j] = Wp3[j * 512 + tid];
    #pragma unroll
    for (int j = 0; j < 32; ++j) PIN4(wv[j]);   // one-time anchor only

    // ---- stage q-col weights to LDS ----
    #pragma unroll
    for (int j = 0; j < 4; ++j) {
        int i = tid * 4 + j;         // 0..2047
        WhqL[i >> 7][i & 127] = Whql[i];
    }

    // ---- per-thread invariants ----
    const bool isCell = (ks < 2);
    const int  r      = ks & 1;      // cell row for isCell lanes
    float4 wqv = make_float4(0.f, 0.f, 0.f, 0.f);
    float bb = 0.f, cxr = 0.f;
    if (isCell) {
        wqv = *(const float4*)(Wq + h * 4);
        bb  = bq[h];
    }
    // q-side invariants (tid<128): qc=tid>>3, rq=(tid>>2)&1, kseg=tid&3
    int qc = 0, rq = 0, kseg = 0, qw = 0, qg = 0;
    float qcoef = 1.f, qth3 = 0.f;
    if (tid < 128) {
        qc = tid >> 3; rq = (tid >> 2) & 1; kseg = tid & 3;
        qg = qc >> 2;  qw = qc & 3;
        const float* thp = (qg == 0) ? thf : (qg == 1) ? thi : (qg == 2) ? thg : tho;
        qcoef = (qw < 3) ? cosf(thp[qw]) : 1.f;
        qth3  = thp[3];
    }
    if (isCell) {
        const float* hs = (t0 == 0) ? hx0 : stateH;
        const float* cs = (t0 == 0) ? cx0 : stateC;
        hL[r][hsk(h)] = hs[(size_t)(row0 + r) * HH + h];
        cxr           = cs[(size_t)(row0 + r) * HH + h];
    }
    __syncthreads();

    for (int tc = 0; tc < TC; ++tc) {
        const float* zrow = Zx + ((size_t)tc * BB + row0) * NCOL;
        // prefetch (latency hidden under GEMM)
        float zc0 = 0, zc1 = 0, zc2 = 0, zc3 = 0, zqv = 0;
        if (isCell) {
            const float* zp = zrow + (size_t)r * NCOL + h;
            zc0 = zp[0]; zc1 = zp[128]; zc2 = zp[256]; zc3 = zp[384];
        }
        if (tid < 128) zqv = zrow[(size_t)rq * NCOL + 512 + qc];

        // ---- h-GEMM: 4 gate-cols (own h) x 32 k x 2 rows ----
        float aF0 = 0, aF1 = 0, aI0 = 0, aI1 = 0, aG0 = 0, aG1 = 0, aO0 = 0, aO1 = 0;
        {
            const float4* h0p = (const float4*)&hL[0][40 * ks];
            const float4* h1p = (const float4*)&hL[1][40 * ks];
            #pragma unroll
            for (int k4 = 0; k4 < 8; ++k4) {
                float4 hv0 = h0p[k4];
                float4 hv1 = h1p[k4];
                FMA4(aF0, wv[k4],      hv0);  FMA4(aF1, wv[k4],      hv1);
                FMA4(aI0, wv[8 + k4],  hv0);  FMA4(aI1, wv[8 + k4],  hv1);
                FMA4(aG0, wv[16 + k4], hv0);  FMA4(aG1, wv[16 + k4], hv1);
                FMA4(aO0, wv[24 + k4], hv0);  FMA4(aO1, wv[24 + k4], hv1);
            }
        }
        // 2-level butterfly over the 4 k-segment lanes
        #define BRED(v) { v += __shfl_xor(v, 1, 64); v += __shfl_xor(v, 2, 64); }
        BRED(aF0) BRED(aF1) BRED(aI0) BRED(aI1)
        BRED(aG0) BRED(aG1) BRED(aO0) BRED(aO1)
        #undef BRED

        // ---- q side (waves 0-1): angle dots + closed-form E ----
        if (tid < 128) {
            float qa = 0.f;
            const float4* hqp = (const float4*)&hL[rq][40 * kseg];
            #pragma unroll
            for (int k4 = 0; k4 < 8; ++k4) {
                float4 wq4 = *(const float4*)&WhqL[qc][kseg * 32 + 4 * k4];
                FMA4(qa, wq4, hqp[k4]);
            }
            qa += __shfl_xor(qa, 1, 64);
            qa += __shfl_xor(qa, 2, 64);
            float a = zqv + qa;
            float c = __cosf(a);
            int lbase = ((qg & 1) * 4) * 8 + rq * 4;   // lane of wire 0 of this (g,rq)
            float cw0 = __shfl(c, lbase, 64);
            float cw1 = __shfl(c, lbase + 8, 64);
            float cw2 = __shfl(c, lbase + 16, 64);
            float own = (qw == 3) ? __cosf(a + qth3) : c;
            float prod = 1.f;
            if (qw >= 1) prod *= cw0;
            if (qw >= 2) prod *= cw1;
            if (qw == 3) prod *= cw2;
            if (kseg == 0) EZ[rq][qg][qw] = qcoef * prod * own;
        }
        __syncthreads();   // EZ visible; all hL reads done

        // ---- fused cell update ----
        if (isCell) {
            float pf = zc0 + (r ? aF1 : aF0);
            float pi = zc1 + (r ? aI1 : aI0);
            float pg = zc2 + (r ? aG1 : aG0);
            float po = zc3 + (r ? aO1 : aO0);
            float4 Ef = *(const float4*)&EZ[r][0][0];
            float4 Ei = *(const float4*)&EZ[r][1][0];
            float4 Eg = *(const float4*)&EZ[r][2][0];
            float4 Eo = *(const float4*)&EZ[r][3][0];
            float qf = fmaf(Ef.x, wqv.x, fmaf(Ef.y, wqv.y, fmaf(Ef.z, wqv.z, fmaf(Ef.w, wqv.w, bb))));
            float qi = fmaf(Ei.x, wqv.x, fmaf(Ei.y, wqv.y, fmaf(Ei.z, wqv.z, fmaf(Ei.w, wqv.w, bb))));
            float qg2 = fmaf(Eg.x, wqv.x, fmaf(Eg.y, wqv.y, fmaf(Eg.z, wqv.z, fmaf(Eg.w, wqv.w, bb))));
            float qo = fmaf(Eo.x, wqv.x, fmaf(Eo.y, wqv.y, fmaf(Eo.z, wqv.z, fmaf(Eo.w, wqv.w, bb))));
            float f  = sigm(pf)   + sigm(qf);
            float ii = sigm(pi)   + sigm(qi);
            float gg = tanh_f(pg) + tanh_f(qg2);
            float oo = sigm(po)   + sigm(qo);
            float cn = fmaf(f, cxr, ii * gg);
            cxr = cn;
            float hn = oo * tanh_f(cn);
            hL[r][hsk(h)] = hn;
            out[((size_t)(t0 + tc) * BB + row0 + r) * HH + h] = hn;
        }
        __syncthreads();   // h_{t+1} visible
    }

    if (isCell) {
        float hn = hL[r][hsk(h)];
        stateH[(size_t)(row0 + r) * HH + h] = hn;
        stateC[(size_t)(row0 + r) * HH + h] = cxr;
        if (t0 + TC == TT) {
            size_t base = (size_t)TT * BB * HH;
            out[base + (size_t)(row0 + r) * HH + h]                   = hn;
            out[base + (size_t)BB * HH + (size_t)(row0 + r) * HH + h] = cxr;
        }
    }
}

extern "C" void kernel_launch(void* const* d_in, const int* in_sizes, int n_in,
                              void* d_out, int out_size, void* d_ws, size_t ws_size,
                              hipStream_t stream) {
    const float* X   = (const float*)d_in[0];
    const float* hx0 = (const float*)d_in[1];
    const float* cx0 = (const float*)d_in[2];
    const float* Wf  = (const float*)d_in[3];
    const float* bf  = (const float*)d_in[4];
    const float* Wfq = (const float*)d_in[5];
    const float* bfq = (const float*)d_in[6];
    const float* thf = (const float*)d_in[7];
    const float* Wi  = (const float*)d_in[8];
    const float* bi  = (const float*)d_in[9];
    const float* Wiq = (const float*)d_in[10];
    const float* biq = (const float*)d_in[11];
    const float* thi = (const float*)d_in[12];
    const float* Wg  = (const float*)d_in[13];
    const float* bg  = (const float*)d_in[14];
    const float* Wgq = (const float*)d_in[15];
    const float* bgq = (const float*)d_in[16];
    const float* thg = (const float*)d_in[17];
    const float* Wo  = (const float*)d_in[18];
    const float* bo  = (const float*)d_in[19];
    const float* Woq = (const float*)d_in[20];
    const float* boq = (const float*)d_in[21];
    const float* tho = (const float*)d_in[22];
    const float* Wq  = (const float*)d_in[23];
    const float* bq  = (const float*)d_in[24];

    float* ws = (float*)d_ws;
    float* Wxp    = ws;                         // 528*128 = 67584
    float* Whr3   = Wxp + 528 * 128;            // 32*512*4 = 65536
    float* Whql   = Whr3 + 65536;               // 16*128 = 2048
    float* bcatp  = Whql + 2048;                // 576
    float* stateH = bcatp + NCPAD;              // 65536
    float* stateC = stateH + 512 * 128;         // 65536
    float* Zxb    = stateC + 512 * 128;

    size_t fixed_bytes = (size_t)(Zxb - ws) * sizeof(float);
    int TC = 256;
    while (TC > 4 && fixed_bytes + (size_t)TC * 512 * NCOL * 4 > ws_size) TC >>= 1;

    pack_weights<<<(NCOL * KK + 255) / 256, 256, 0, stream>>>(
        Wf, bf, Wfq, bfq, Wi, bi, Wiq, biq, Wg, bg, Wgq, bgq, Wo, bo, Woq, boq,
        Wxp, Whr3, Whql, bcatp);

    for (int t0 = 0; t0 < TT; t0 += TC) {
        xgemm<<<dim3(TC * 512 / P1_BM, NCPAD / P1_BN), 256, 0, stream>>>(
            X + (size_t)t0 * BB * DD, Wxp, bcatp, Zxb);
        qlstm_rec<<<256, 512, 0, stream>>>(
            Zxb, Whr3, Whql, hx0, cx0, stateH, stateC, Wq, bq,
            thf, thi, thg, tho, (float*)d_out, t0, TC);
    }
}